// Round 1
// baseline (320.665 us; speedup 1.0000x reference)
//
#include <hip/hip_runtime.h>
#include <cstdint>
#include <cstddef>

// Problem constants (B,H,L,D,k) = (4,1,2048,512,4), SHIFTS = {1,2,4}
#define D_DIM 512
#define K_DIM 3072   // 6 groups of 512: (s=1 diff, s=1 silu, s=2 diff, s=2 silu, s=4 diff, s=4 silu)
#define L_DIM 2048
#define M_TOT 32768  // B * L * k

typedef __bf16 bf16x8 __attribute__((ext_vector_type(8)));
typedef float  f32x4  __attribute__((ext_vector_type(4)));

__device__ __forceinline__ unsigned short f2bf(float f) {
  unsigned u = __float_as_uint(f);
  u += 0x7FFF + ((u >> 16) & 1);   // RNE
  return (unsigned short)(u >> 16);
}
__device__ __forceinline__ float bf2f(unsigned short u) {
  return __uint_as_float(((unsigned)u) << 16);
}

__device__ __forceinline__ void gld_lds16(const void* g, void* l) {
  __builtin_amdgcn_global_load_lds((const __attribute__((address_space(1))) void*)g,
                                   (__attribute__((address_space(3))) void*)l,
                                   16, 0, 0);
}

// ---------------- pre-pass: P[k][d] fp32 -> PT[d][k] bf16 ----------------
__global__ void transpose_convert(const float* __restrict__ P, unsigned short* __restrict__ PT) {
  __shared__ float tile[32][33];
  const int k0 = blockIdx.x * 32;
  const int d0 = blockIdx.y * 32;
  const int tx = threadIdx.x, ty = threadIdx.y;  // 32 x 8
  #pragma unroll
  for (int i = 0; i < 32; i += 8)
    tile[ty + i][tx] = P[(size_t)(k0 + ty + i) * D_DIM + d0 + tx];
  __syncthreads();
  #pragma unroll
  for (int i = 0; i < 32; i += 8)
    PT[(size_t)(d0 + ty + i) * K_DIM + k0 + tx] = f2bf(tile[tx][ty + i]);
}

// ---------------- fused g-generation + GEMM ----------------
// Computes g value for K index c in group gi: s = 1<<(gi>>1), silu = gi&1
//   sw = v[cc] * w[(cc-s)%512]
//   diff: sw - w[cc] * v[(cc-s)%512];  silu: sw*sigmoid(sw)
template<int S, bool SILU>
__device__ __forceinline__ void stageA(const unsigned short* vptr, const float* wptr,
                                       int ccbase, unsigned short* aout) {
  const int lowIdx = (ccbase - 8) & 511;  // handles mod-512 wrap when ccbase == 0
  alignas(16) unsigned short varr[24];
  alignas(16) float warr[24];
  if constexpr (!SILU) {
    *reinterpret_cast<uint4*>(&varr[0]) = *reinterpret_cast<const uint4*>(&vptr[lowIdx]);
  }
  *reinterpret_cast<uint4*>(&varr[8])   = *reinterpret_cast<const uint4*>(&vptr[ccbase]);
  *reinterpret_cast<uint4*>(&varr[16])  = *reinterpret_cast<const uint4*>(&vptr[ccbase + 8]);
  *reinterpret_cast<float4*>(&warr[0])  = *reinterpret_cast<const float4*>(&wptr[lowIdx]);
  *reinterpret_cast<float4*>(&warr[4])  = *reinterpret_cast<const float4*>(&wptr[lowIdx + 4]);
  *reinterpret_cast<float4*>(&warr[8])  = *reinterpret_cast<const float4*>(&wptr[ccbase]);
  *reinterpret_cast<float4*>(&warr[12]) = *reinterpret_cast<const float4*>(&wptr[ccbase + 4]);
  *reinterpret_cast<float4*>(&warr[16]) = *reinterpret_cast<const float4*>(&wptr[ccbase + 8]);
  *reinterpret_cast<float4*>(&warr[20]) = *reinterpret_cast<const float4*>(&wptr[ccbase + 12]);
  alignas(16) unsigned short res[16];
  #pragma unroll
  for (int e = 0; e < 16; ++e) {
    float sw = bf2f(varr[8 + e]) * warr[8 + e - S];
    float g;
    if constexpr (SILU) {
      g = sw * __builtin_amdgcn_rcpf(1.0f + __expf(-sw));
    } else {
      g = sw - warr[8 + e] * bf2f(varr[8 + e - S]);
    }
    res[e] = f2bf(g);
  }
  *reinterpret_cast<uint4*>(&aout[0]) = *reinterpret_cast<const uint4*>(&res[0]);
  *reinterpret_cast<uint4*>(&aout[8]) = *reinterpret_cast<const uint4*>(&res[8]);
}

__global__ __launch_bounds__(256, 2) void fused_gemm(
    const float* __restrict__ x, const float* __restrict__ W,
    const float* __restrict__ bias, const unsigned short* __restrict__ PT,
    float* __restrict__ out) {
  __shared__ unsigned short xs[33 * D_DIM];   // rows l0-1 .. l0+31 as bf16 (33,792 B)
  __shared__ float Wl[4 * D_DIM];             // 8,192 B
  __shared__ unsigned short Atile[128 * 40];  // 32 used + 8 pad -> 80 B rows (10,240 B)
  __shared__ unsigned short Btile[128 * 32];  // swizzled 16B slots (8,192 B)

  const int tid = threadIdx.x;
  const int nt = blockIdx.x & 3;      // 4 N-tiles
  const int mt = blockIdx.x >> 2;     // 256 M-tiles
  const int n0 = nt * 128;
  const int b  = mt >> 6;             // 64 M-tiles per batch element
  const int l0 = (mt & 63) * 32;

  // ---- stage W (fp32) ----
  {
    const float4* W4 = reinterpret_cast<const float4*>(W);
    float4* Wl4 = reinterpret_cast<float4*>(Wl);
    Wl4[tid] = W4[tid];
    Wl4[tid + 256] = W4[tid + 256];
  }
  // ---- stage x rows (bf16): row i = x[b, l0-1+i, :], zeros if l<0 ----
  {
    const float4* xb = reinterpret_cast<const float4*>(x + (size_t)b * L_DIM * D_DIM);
    for (int i = tid; i < 33 * 128; i += 256) {
      const int row = i >> 7;
      const int c4 = i & 127;
      const int l = l0 - 1 + row;
      float4 v = {0.f, 0.f, 0.f, 0.f};
      if (l >= 0) v = xb[(size_t)l * 128 + c4];
      uint2 p;
      p.x = (unsigned)f2bf(v.x) | ((unsigned)f2bf(v.y) << 16);
      p.y = (unsigned)f2bf(v.z) | ((unsigned)f2bf(v.w) << 16);
      *reinterpret_cast<uint2*>(&xs[row * D_DIM + c4 * 4]) = p;
    }
  }

  // ---- per-thread A-staging geometry: thread t covers row m=t>>1, k-half (t&1)*16 ----
  const int am = tid >> 1;
  const int akh = (tid & 1) * 16;
  const int aj = am & 3;                                // W row
  const int avrow = (am >> 2) + (aj == 3 ? 1 : 0);      // j<3 -> x[l-1], j==3 -> x[l]
  const unsigned short* vptr = &xs[avrow * D_DIM];
  const float* wptr = &Wl[aj * D_DIM];
  unsigned short* aout = &Atile[am * 40 + akh];

  // ---- B staging geometry (global_load_lds is uniform-base + lane*16) ----
  // slot s holds PT[n0 + n][kk0 + q*8 .. +8) with n = s>>2, q = (s&3) ^ ((n>>2)&3)
  const int bn = tid >> 2;
  const int bq = (tid & 3) ^ ((bn >> 2) & 3);
  const unsigned short* gB0 = PT + (size_t)(n0 + bn) * K_DIM + bq * 8;
  const unsigned short* gB1 = gB0 + (size_t)64 * K_DIM;

  // ---- MFMA geometry: 4 waves in 2x2, each wave 64x64 = 4x4 tiles of 16x16 ----
  const int lane = tid & 63;
  const int wv = tid >> 6;
  const int wm = wv >> 1;
  const int wn = wv & 1;
  const int l16 = lane & 15;
  const int quad = lane >> 4;
  const unsigned short* afp = &Atile[(wm * 64 + l16) * 40 + quad * 8];

  f32x4 acc[4][4];
  #pragma unroll
  for (int i = 0; i < 4; ++i)
    #pragma unroll
    for (int j = 0; j < 4; ++j)
      acc[i][j] = f32x4{0.f, 0.f, 0.f, 0.f};

  for (int kk0 = 0; kk0 < K_DIM; kk0 += 32) {
    __syncthreads();  // prev-iter frag reads done (and xs/W staging on iter 0)
    // B tile: 2 x 4096 B via global_load_lds width-16
    gld_lds16(gB0 + kk0, &Btile[tid * 8]);
    gld_lds16(gB1 + kk0, &Btile[2048 + tid * 8]);
    // A tile: compute g on the fly
    const int gi = kk0 >> 9;
    const int ccbase = (kk0 & 511) + akh;
    switch (gi) {
      case 0: stageA<1, false>(vptr, wptr, ccbase, aout); break;
      case 1: stageA<1, true >(vptr, wptr, ccbase, aout); break;
      case 2: stageA<2, false>(vptr, wptr, ccbase, aout); break;
      case 3: stageA<2, true >(vptr, wptr, ccbase, aout); break;
      case 4: stageA<4, false>(vptr, wptr, ccbase, aout); break;
      default: stageA<4, true >(vptr, wptr, ccbase, aout); break;
    }
    __syncthreads();  // compiler drains vmcnt before barrier -> B tile ready

    bf16x8 af[4], bfr[4];
    #pragma unroll
    for (int mi = 0; mi < 4; ++mi) {
      uint4 r = *reinterpret_cast<const uint4*>(afp + mi * 16 * 40);
      af[mi] = __builtin_bit_cast(bf16x8, r);
    }
    #pragma unroll
    for (int ni = 0; ni < 4; ++ni) {
      const int n = wn * 64 + ni * 16 + l16;
      const int slot = n * 4 + (quad ^ ((n >> 2) & 3));
      uint4 r = *reinterpret_cast<const uint4*>(&Btile[slot * 8]);
      bfr[ni] = __builtin_bit_cast(bf16x8, r);
    }
    #pragma unroll
    for (int mi = 0; mi < 4; ++mi)
      #pragma unroll
      for (int ni = 0; ni < 4; ++ni)
        acc[mi][ni] = __builtin_amdgcn_mfma_f32_16x16x32_bf16(af[mi], bfr[ni], acc[mi][ni], 0, 0, 0);
  }

  // ---- epilogue: C/D layout col = lane&15, row = quad*4 + reg ----
  #pragma unroll
  for (int ni = 0; ni < 4; ++ni) {
    const int d = n0 + wn * 64 + ni * 16 + l16;
    const float bv = bias[d];
    #pragma unroll
    for (int mi = 0; mi < 4; ++mi) {
      const int rbase = mt * 128 + wm * 64 + mi * 16 + quad * 4;
      #pragma unroll
      for (int rg = 0; rg < 4; ++rg) {
        out[(size_t)(rbase + rg) * D_DIM + d] = acc[mi][ni][rg] + bv;
      }
    }
  }
}

extern "C" void kernel_launch(void* const* d_in, const int* in_sizes, int n_in,
                              void* d_out, int out_size, void* d_ws, size_t ws_size,
                              hipStream_t stream) {
  const float* x    = (const float*)d_in[0];  // (4,1,2048,512) fp32
  const float* W    = (const float*)d_in[1];  // (4,512) fp32
  const float* P    = (const float*)d_in[2];  // (3072,512) fp32
  const float* bias = (const float*)d_in[3];  // (512,) fp32
  float* out = (float*)d_out;                 // (4,1,8192,512) fp32
  unsigned short* PT = (unsigned short*)d_ws; // 512*3072 bf16 = 3 MiB

  transpose_convert<<<dim3(K_DIM / 32, D_DIM / 32), dim3(32, 8), 0, stream>>>(P, PT);
  fused_gemm<<<dim3(1024), dim3(256), 0, stream>>>(x, W, bias, PT, out);
}

// Round 2
// 201.582 us; speedup vs baseline: 1.5907x; 1.5907x over previous
//
#include <hip/hip_runtime.h>
#include <cstdint>
#include <cstddef>

// (B,H,L,D,k) = (4,1,2048,512,4), SHIFTS = {1,2,4}
// Folded problem: out[(b,l,j),d] = sum_c v[c]*Qj[c,d]  (diff groups, K=512)
//                               + sum_{si,c} silu(v[c]*W[j,(c-s)%512]) * Psilu[si,c,d]  (K=1536)
// with v = x[b,l-1] for j<3, x[b,l] for j==3.
#define D_DIM 512
#define L_DIM 2048
#define KB_DIM 2048    // 512 diff + 3*512 silu
#define NROWS_X 2049   // per-b rows in XbfZ; row 0 is zeros (the l=-1 pad)

typedef __bf16 bf16x8 __attribute__((ext_vector_type(8)));
typedef float  f32x4  __attribute__((ext_vector_type(4)));

__device__ __forceinline__ unsigned f2bf(float f) {
  unsigned u = __float_as_uint(f);
  u += 0x7FFF + ((u >> 16) & 1);   // RNE
  return u >> 16;
}
__device__ __forceinline__ float bf2f(unsigned short u) {
  return __uint_as_float(((unsigned)u) << 16);
}
__device__ __forceinline__ void gld_lds16(const void* g, void* l) {
  __builtin_amdgcn_global_load_lds((const __attribute__((address_space(1))) void*)g,
                                   (__attribute__((address_space(3))) void*)l,
                                   16, 0, 0);
}

// ---------------- prepass 1: x fp32 -> XbfZ bf16 with per-b zero row at index 0 ----
__global__ void convert_x(const float* __restrict__ x, unsigned short* __restrict__ XbfZ) {
  const int b = blockIdx.y;
  const int idx = blockIdx.x * 256 + threadIdx.x;   // over 2049*128 uint2-groups
  if (idx >= NROWS_X * 128) return;
  const int rr = idx >> 7;       // 0..2048 ; rr==0 -> zero row
  const int c4 = idx & 127;
  uint2 p = {0u, 0u};
  if (rr > 0) {
    float4 v = reinterpret_cast<const float4*>(x)[((size_t)b * L_DIM + rr - 1) * 128 + c4];
    p.x = f2bf(v.x) | (f2bf(v.y) << 16);
    p.y = f2bf(v.z) | (f2bf(v.w) << 16);
  }
  reinterpret_cast<uint2*>(XbfZ)[((size_t)b * NROWS_X + rr) * 128 + c4] = p;
}

// ---------------- prepass 2: build Ball[j][d][k] bf16 (k-major rows) ----------------
// k in [0,512): Qj fold:  sum_si W[j,(c-s)]*P[2si*512+c][d] - W[j,(c+s)]*P[2si*512+(c+s)][d]
// k in [512+si*512, +512): Psilu: P[(2si+1)*512+c][d]
__global__ void build_B(const float* __restrict__ P, const float* __restrict__ W,
                        unsigned short* __restrict__ Ball) {
  const int bx = blockIdx.x;             // 256 blocks
  const int j = bx >> 6, dt = (bx >> 3) & 7, ct = bx & 7;
  const int t = threadIdx.x;
  const int d = dt * 64 + (t & 63);
  const int cbase = ct * 64 + (t >> 6) * 16;
  unsigned short bufd[16];
  unsigned short bufs[3][16];
  #pragma unroll
  for (int cc = 0; cc < 16; ++cc) {
    const int c = cbase + cc;
    float qd = 0.f;
    #pragma unroll
    for (int si = 0; si < 3; ++si) {
      const int s = 1 << si;
      const int cm = (c - s) & 511, cp = (c + s) & 511;
      qd += W[j * 512 + cm] * P[((size_t)(2 * si) * 512 + c) * 512 + d]
          - W[j * 512 + cp] * P[((size_t)(2 * si) * 512 + cp) * 512 + d];
      bufs[si][cc] = (unsigned short)f2bf(P[((size_t)(2 * si + 1) * 512 + c) * 512 + d]);
    }
    bufd[cc] = (unsigned short)f2bf(qd);
  }
  unsigned short* row = Ball + (size_t)(j * 512 + d) * KB_DIM;
  *reinterpret_cast<uint4*>(&row[cbase])     = *reinterpret_cast<uint4*>(&bufd[0]);
  *reinterpret_cast<uint4*>(&row[cbase + 8]) = *reinterpret_cast<uint4*>(&bufd[8]);
  #pragma unroll
  for (int si = 0; si < 3; ++si) {
    *reinterpret_cast<uint4*>(&row[512 + si * 512 + cbase])     = *reinterpret_cast<uint4*>(&bufs[si][0]);
    *reinterpret_cast<uint4*>(&row[512 + si * 512 + cbase + 8]) = *reinterpret_cast<uint4*>(&bufs[si][8]);
  }
}

// ---------------- fused j-grouped GEMM ----------------
__global__ __launch_bounds__(256, 2) void fused_gemm(
    const unsigned short* __restrict__ XbfZ, const unsigned short* __restrict__ Ball,
    const float* __restrict__ W, const float* __restrict__ bias,
    float* __restrict__ out) {
  __shared__ alignas(16) unsigned short Vt[2][4096];   // 128 rows x 32k, swizzled 16B slots
  __shared__ alignas(16) unsigned short Bt[2][8192];   // 256 rows x 32k, swizzled
  __shared__ alignas(16) unsigned short At[128 * 40];  // silu A tile, +8 pad
  __shared__ alignas(16) unsigned short Wr[3 * 512];   // pre-rolled W[j], bf16

  const int tid = threadIdx.x;
  const int nt = blockIdx.x & 1;
  const int mt = blockIdx.x >> 1;        // 256
  const int j  = mt >> 6;
  const int b  = (mt >> 4) & 3;
  const int lt = mt & 15;
  const int l0 = lt * 128;
  const int n0 = nt * 256;
  const int base_l = l0 - ((j == 3) ? 0 : 1);

  // ---- stage pre-rolled W (bf16) ----
  #pragma unroll
  for (int i = 0; i < 6; ++i) {
    const int idx = tid + i * 256;       // < 1536
    const int si = idx >> 9, c = idx & 511, s = 1 << si;
    Wr[idx] = (unsigned short)f2bf(W[j * 512 + ((c - s) & 511)]);
  }

  // ---- gld geometry: slot p*64+lane holds row m=p*16+(lane>>2), chunk q = (lane&3)^((lane>>4)&3) ----
  const int lane = tid & 63, wv = tid >> 6;
  const int qv = (lane & 3) ^ ((lane >> 4) & 3);
  const int rsub = lane >> 2;
  const unsigned short* gA0 = XbfZ + ((size_t)(b * NROWS_X + 1 + base_l + (wv * 2) * 16 + rsub)) * 512 + qv * 8;
  const unsigned short* gA1 = gA0 + (size_t)16 * 512;
  const unsigned short* gB[4];
  #pragma unroll
  for (int pi = 0; pi < 4; ++pi)
    gB[pi] = Ball + (size_t)(j * 512 + n0 + (wv * 4 + pi) * 16 + rsub) * KB_DIM + qv * 8;
  const int vOff0 = wv * 1024 + lane * 8;   // shorts
  const int bOff0 = wv * 2048 + lane * 8;

  // ---- silu staging geometry: thread -> row am, k-half akh ----
  const int am = tid >> 1;
  const int akh = (tid & 1) * 16;
  const int ch0 = (tid & 1) * 2;
  const int sswz = (am >> 2) & 3;
  unsigned short* aDst = &At[am * 40 + akh];

  // ---- MFMA frag geometry: 4 waves 2x2, wave = 64M x 128N ----
  const int l16 = lane & 15, quad = lane >> 4;
  const int wm = wv >> 1, wn = wv & 1;
  const int fsw = (l16 >> 2) & 3;
  const int aVoff = (wm * 64 + l16) * 32 + ((quad ^ fsw)) * 8;  // Vt, diff iters
  const int aSoff = (wm * 64 + l16) * 40 + quad * 8;            // At, silu iters
  const int bOffF = (wn * 128 + l16) * 32 + ((quad ^ fsw)) * 8; // Bt

  f32x4 acc[4][8];
  #pragma unroll
  for (int i = 0; i < 4; ++i)
    #pragma unroll
    for (int n = 0; n < 8; ++n)
      acc[i][n] = f32x4{0.f, 0.f, 0.f, 0.f};

  // prefetch iter 0
  {
    gld_lds16(gA0, &Vt[0][vOff0]);
    gld_lds16(gA1, &Vt[0][vOff0 + 512]);
    #pragma unroll
    for (int pi = 0; pi < 4; ++pi)
      gld_lds16(gB[pi], &Bt[0][bOff0 + pi * 512]);
  }

  for (int it = 0; it < 64; ++it) {
    const int buf = it & 1;
    const int kk0 = it * 32;
    const int gi = kk0 >> 9;             // 0 = diff, 1..3 = silu group si=gi-1

    __syncthreads();  // drains this buf's glds; protects At & retired buf reuse

    if (it + 1 < 64) {                   // issue next tile into other buffer
      const int nk = kk0 + 32;
      const int nv = nk & 511;
      gld_lds16(gA0 + nv, &Vt[buf ^ 1][vOff0]);
      gld_lds16(gA1 + nv, &Vt[buf ^ 1][vOff0 + 512]);
      #pragma unroll
      for (int pi = 0; pi < 4; ++pi)
        gld_lds16(gB[pi] + nk, &Bt[buf ^ 1][bOff0 + pi * 512]);
    }

    bf16x8 af[4], bfr[8];
    if (gi == 0) {
      // diff: A = v directly from Vt (swizzled)
      #pragma unroll
      for (int mi = 0; mi < 4; ++mi) {
        uint4 r = *reinterpret_cast<const uint4*>(&Vt[buf][aVoff + mi * 512]);
        af[mi] = __builtin_bit_cast(bf16x8, r);
      }
    } else {
      // silu: stage A tile from Vt + Wr
      const int si = gi - 1;
      const int ccbase = (kk0 & 511) + akh;
      uint4 v0 = *reinterpret_cast<const uint4*>(&Vt[buf][(am * 4 + ((ch0)     ^ sswz)) * 8]);
      uint4 v1 = *reinterpret_cast<const uint4*>(&Vt[buf][(am * 4 + ((ch0 + 1) ^ sswz)) * 8]);
      uint4 w0 = *reinterpret_cast<const uint4*>(&Wr[si * 512 + ccbase]);
      uint4 w1 = *reinterpret_cast<const uint4*>(&Wr[si * 512 + ccbase + 8]);
      union U { uint4 q[2]; unsigned short s[16]; };
      U va, wa; va.q[0] = v0; va.q[1] = v1; wa.q[0] = w0; wa.q[1] = w1;
      unsigned res[8];
      #pragma unroll
      for (int e = 0; e < 8; ++e) {
        float s0 = bf2f(va.s[2 * e])     * bf2f(wa.s[2 * e]);
        float s1 = bf2f(va.s[2 * e + 1]) * bf2f(wa.s[2 * e + 1]);
        float g0 = s0 * __builtin_amdgcn_rcpf(1.f + __expf(-s0));
        float g1 = s1 * __builtin_amdgcn_rcpf(1.f + __expf(-s1));
        res[e] = f2bf(g0) | (f2bf(g1) << 16);
      }
      uint4 o0 = {res[0], res[1], res[2], res[3]};
      uint4 o1 = {res[4], res[5], res[6], res[7]};
      *reinterpret_cast<uint4*>(aDst) = o0;
      *reinterpret_cast<uint4*>(aDst + 8) = o1;
      __syncthreads();  // At ready (block-uniform branch)
      #pragma unroll
      for (int mi = 0; mi < 4; ++mi) {
        uint4 r = *reinterpret_cast<const uint4*>(&At[aSoff + mi * 640]);
        af[mi] = __builtin_bit_cast(bf16x8, r);
      }
    }
    #pragma unroll
    for (int ni = 0; ni < 8; ++ni) {
      uint4 r = *reinterpret_cast<const uint4*>(&Bt[buf][bOffF + ni * 512]);
      bfr[ni] = __builtin_bit_cast(bf16x8, r);
    }
    #pragma unroll
    for (int mi = 0; mi < 4; ++mi)
      #pragma unroll
      for (int ni = 0; ni < 8; ++ni)
        acc[mi][ni] = __builtin_amdgcn_mfma_f32_16x16x32_bf16(af[mi], bfr[ni], acc[mi][ni], 0, 0, 0);
  }

  // ---- epilogue: C/D col = lane&15 (N), row = quad*4+reg (M) ----
  #pragma unroll
  for (int ni = 0; ni < 8; ++ni) {
    const int d = n0 + wn * 128 + ni * 16 + l16;
    const float bv = bias[d];
    #pragma unroll
    for (int mi = 0; mi < 4; ++mi) {
      const int lrow = l0 + wm * 64 + mi * 16 + quad * 4;
      #pragma unroll
      for (int rg = 0; rg < 4; ++rg) {
        out[((size_t)(b * L_DIM + lrow + rg) * 4 + j) * D_DIM + d] = acc[mi][ni][rg] + bv;
      }
    }
  }
}

extern "C" void kernel_launch(void* const* d_in, const int* in_sizes, int n_in,
                              void* d_out, int out_size, void* d_ws, size_t ws_size,
                              hipStream_t stream) {
  const float* x    = (const float*)d_in[0];  // (4,1,2048,512) fp32
  const float* W    = (const float*)d_in[1];  // (4,512) fp32
  const float* P    = (const float*)d_in[2];  // (3072,512) fp32
  const float* bias = (const float*)d_in[3];  // (512,) fp32
  float* out = (float*)d_out;                 // (4,1,8192,512) fp32

  unsigned short* XbfZ = (unsigned short*)d_ws;                  // 4*2049*512 bf16 = 8.39 MB
  unsigned short* Ball = XbfZ + (size_t)4 * NROWS_X * 512;       // 4*512*2048 bf16 = 8.39 MB

  convert_x<<<dim3(1025, 4), 256, 0, stream>>>(x, XbfZ);
  build_B<<<256, 256, 0, stream>>>(P, W, Ball);
  fused_gemm<<<512, 256, 0, stream>>>(XbfZ, Ball, W, bias, out);
}

// Round 3
// 199.434 us; speedup vs baseline: 1.6079x; 1.0108x over previous
//
#include <hip/hip_runtime.h>
#include <cstdint>
#include <cstddef>

// (B,H,L,D,k) = (4,1,2048,512,4), SHIFTS = {1,2,4}
// Folded: out[(b,l,j),d] = sum_c v[c]*Qj[c,d]               (diff, K=512)
//                        + sum_{si,c} silu(v[c]*W[j,(c-s)%512]) * Psilu[si,c,d]  (K=1536)
// v = x[b,l-1] for j<3, x[b,l] for j==3.
// Round 3: silu A-matrix GS materialized in a prepass; hot GEMM is pure m97-style
// (1 barrier/iter, dbuf, global_load_lds w=16). Fallback to round-2 fused kernel
// if ws_size < ~112 MB.
#define D_DIM 512
#define L_DIM 2048
#define KB_DIM 2048    // 512 diff + 3*512 silu
#define KS_DIM 1536
#define NROWS_X 2049   // per-b rows in XbfZ; row 0 is zeros (the l=-1 pad)
#define M_TOT 32768

typedef __bf16 bf16x8 __attribute__((ext_vector_type(8)));
typedef float  f32x4  __attribute__((ext_vector_type(4)));

__device__ __forceinline__ unsigned f2bf(float f) {
  unsigned u = __float_as_uint(f);
  u += 0x7FFF + ((u >> 16) & 1);   // RNE
  return u >> 16;
}
__device__ __forceinline__ float bf2f(unsigned short u) {
  return __uint_as_float(((unsigned)u) << 16);
}
__device__ __forceinline__ void gld_lds16(const void* g, void* l) {
  __builtin_amdgcn_global_load_lds((const __attribute__((address_space(1))) void*)g,
                                   (__attribute__((address_space(3))) void*)l,
                                   16, 0, 0);
}

// ---------------- prepass 1: x fp32 -> XbfZ bf16 with per-b zero row at index 0 ----
__global__ void convert_x(const float* __restrict__ x, unsigned short* __restrict__ XbfZ) {
  const int b = blockIdx.y;
  const int idx = blockIdx.x * 256 + threadIdx.x;   // over 2049*128 uint2-groups
  if (idx >= NROWS_X * 128) return;
  const int rr = idx >> 7;       // 0..2048 ; rr==0 -> zero row
  const int c4 = idx & 127;
  uint2 p = {0u, 0u};
  if (rr > 0) {
    float4 v = reinterpret_cast<const float4*>(x)[((size_t)b * L_DIM + rr - 1) * 128 + c4];
    p.x = f2bf(v.x) | (f2bf(v.y) << 16);
    p.y = f2bf(v.z) | (f2bf(v.w) << 16);
  }
  reinterpret_cast<uint2*>(XbfZ)[((size_t)b * NROWS_X + rr) * 128 + c4] = p;
}

// ---------------- prepass 2: build Ball[j][d][k] bf16 (k-major rows) + Wtab ----------
__global__ void build_B(const float* __restrict__ P, const float* __restrict__ W,
                        unsigned short* __restrict__ Ball,
                        unsigned short* __restrict__ Wtab, int buildWtab) {
  if (buildWtab && blockIdx.x == 0) {
    for (int i = threadIdx.x; i < 6144; i += 256) {
      const int c = i & 511; const int rest = i >> 9;
      const int si = rest % 3; const int jj = rest / 3;
      Wtab[(jj * 3 + si) * 512 + c] =
          (unsigned short)f2bf(W[jj * 512 + ((c - (1 << si)) & 511)]);
    }
  }
  const int bx = blockIdx.x;             // 256 blocks
  const int j = bx >> 6, dt = (bx >> 3) & 7, ct = bx & 7;
  const int t = threadIdx.x;
  const int d = dt * 64 + (t & 63);
  const int cbase = ct * 64 + (t >> 6) * 16;
  unsigned short bufd[16];
  unsigned short bufs[3][16];
  #pragma unroll
  for (int cc = 0; cc < 16; ++cc) {
    const int c = cbase + cc;
    float qd = 0.f;
    #pragma unroll
    for (int si = 0; si < 3; ++si) {
      const int s = 1 << si;
      const int cm = (c - s) & 511, cp = (c + s) & 511;
      qd += W[j * 512 + cm] * P[((size_t)(2 * si) * 512 + c) * 512 + d]
          - W[j * 512 + cp] * P[((size_t)(2 * si) * 512 + cp) * 512 + d];
      bufs[si][cc] = (unsigned short)f2bf(P[((size_t)(2 * si + 1) * 512 + c) * 512 + d]);
    }
    bufd[cc] = (unsigned short)f2bf(qd);
  }
  unsigned short* row = Ball + (size_t)(j * 512 + d) * KB_DIM;
  *reinterpret_cast<uint4*>(&row[cbase])     = *reinterpret_cast<uint4*>(&bufd[0]);
  *reinterpret_cast<uint4*>(&row[cbase + 8]) = *reinterpret_cast<uint4*>(&bufd[8]);
  #pragma unroll
  for (int si = 0; si < 3; ++si) {
    *reinterpret_cast<uint4*>(&row[512 + si * 512 + cbase])     = *reinterpret_cast<uint4*>(&bufs[si][0]);
    *reinterpret_cast<uint4*>(&row[512 + si * 512 + cbase + 8]) = *reinterpret_cast<uint4*>(&bufs[si][8]);
  }
}

// ---------------- prepass 3: materialize silu A: GS[(j,b,l)][si*512+c] bf16 ----------
__global__ void gs_gen(const unsigned short* __restrict__ XbfZ,
                       const unsigned short* __restrict__ Wtab,
                       unsigned short* __restrict__ GS) {
  const int m0 = blockIdx.x * 4;          // 8192 blocks, 4 rows each
  const int j = m0 >> 13, b = (m0 >> 11) & 3, lbase = m0 & 2047;
  const int r = threadIdx.x >> 6, lane = threadIdx.x & 63;
  const int l = lbase + r;
  const size_t vrow = (size_t)b * NROWS_X + l + (j == 3);
  union U { uint4 q; unsigned short s[8]; };
  U va;
  va.q = *reinterpret_cast<const uint4*>(XbfZ + vrow * 512 + lane * 8);
  unsigned short* o = GS + (size_t)(m0 + r) * KS_DIM + lane * 8;
  #pragma unroll
  for (int si = 0; si < 3; ++si) {
    U wa;
    wa.q = *reinterpret_cast<const uint4*>(Wtab + (j * 3 + si) * 512 + lane * 8);
    unsigned res[4];
    #pragma unroll
    for (int e = 0; e < 4; ++e) {
      float s0 = bf2f(va.s[2 * e])     * bf2f(wa.s[2 * e]);
      float s1 = bf2f(va.s[2 * e + 1]) * bf2f(wa.s[2 * e + 1]);
      float g0 = s0 * __builtin_amdgcn_rcpf(1.f + __expf(-s0));
      float g1 = s1 * __builtin_amdgcn_rcpf(1.f + __expf(-s1));
      res[e] = f2bf(g0) | (f2bf(g1) << 16);
    }
    uint4 ov = {res[0], res[1], res[2], res[3]};
    *reinterpret_cast<uint4*>(o + si * 512) = ov;
  }
}

// ---------------- main GEMM: m97-style, 128x128 tile, 1 barrier/iter ----------------
__global__ __launch_bounds__(256) void gemm_main(
    const unsigned short* __restrict__ XbfZ, const unsigned short* __restrict__ GS,
    const unsigned short* __restrict__ Ball, const float* __restrict__ bias,
    float* __restrict__ out) {
  __shared__ alignas(16) unsigned short At[2][4096];  // 128 rows x 32k, swizzled 16B slots
  __shared__ alignas(16) unsigned short Bt[2][4096];

  const int tid = threadIdx.x;
  const int bx = blockIdx.x;
  const int nt = bx >> 8;                // 0..3   (mt-contiguous per XCD for L2)
  const int mt = bx & 255;
  const int j  = mt >> 6;
  const int b  = (mt >> 4) & 3;
  const int l0 = (mt & 15) * 128;
  const int n0 = nt * 128;

  // ---- staging geometry: slot s = row*4 + (q ^ ((row>>2)&3)); thread covers s=tid, s=tid+256
  const int rA = tid >> 2;                      // 0..63 (second slot: row 64+rA, same swizzle phase)
  const int qA = (tid & 3) ^ ((rA >> 2) & 3);
  const unsigned short* srcAd0 = XbfZ + (size_t)(b * NROWS_X + l0 + (j == 3) + rA) * 512 + qA * 8;
  const unsigned short* srcAd1 = srcAd0 + (size_t)64 * 512;
  const size_t mbase = (size_t)((j * 4 + b) * L_DIM + l0);
  const unsigned short* srcAs0 = GS + (mbase + rA) * KS_DIM + qA * 8;
  const unsigned short* srcAs1 = srcAs0 + (size_t)64 * KS_DIM;
  const unsigned short* srcB0 = Ball + (size_t)(j * 512 + n0 + rA) * KB_DIM + qA * 8;
  const unsigned short* srcB1 = srcB0 + (size_t)64 * KB_DIM;

  // ---- MFMA frag geometry: 4 waves 2x2, wave 64x64 ----
  const int lane = tid & 63, wv = tid >> 6;
  const int wm = wv >> 1, wn = wv & 1;
  const int l16 = lane & 15, quad = lane >> 4;
  const int qf = quad ^ ((l16 >> 2) & 3);
  const int aBase = (wm * 64 + l16) * 32 + qf * 8;
  const int bBase = (wn * 64 + l16) * 32 + qf * 8;

  f32x4 acc[4][4];
  #pragma unroll
  for (int i = 0; i < 4; ++i)
    #pragma unroll
    for (int n = 0; n < 4; ++n)
      acc[i][n] = f32x4{0.f, 0.f, 0.f, 0.f};

  // prefetch it=0 (diff source)
  gld_lds16(srcAd0, &At[0][tid * 8]);
  gld_lds16(srcAd1, &At[0][(tid + 256) * 8]);
  gld_lds16(srcB0,  &Bt[0][tid * 8]);
  gld_lds16(srcB1,  &Bt[0][(tid + 256) * 8]);

  for (int it = 0; it < 64; ++it) {
    const int buf = it & 1;
    __syncthreads();   // drains glds(it) issued one full iteration ago
    if (it + 1 < 64) {
      const int nx = it + 1, nb = buf ^ 1;
      const unsigned short *a0, *a1;
      if (nx < 16) { a0 = srcAd0 + nx * 32; a1 = srcAd1 + nx * 32; }
      else { const int o = (nx - 16) * 32; a0 = srcAs0 + o; a1 = srcAs1 + o; }
      gld_lds16(a0, &At[nb][tid * 8]);
      gld_lds16(a1, &At[nb][(tid + 256) * 8]);
      gld_lds16(srcB0 + nx * 32, &Bt[nb][tid * 8]);
      gld_lds16(srcB1 + nx * 32, &Bt[nb][(tid + 256) * 8]);
    }
    bf16x8 af[4], bfr[4];
    #pragma unroll
    for (int mi = 0; mi < 4; ++mi) {
      uint4 rr = *reinterpret_cast<const uint4*>(&At[buf][aBase + mi * 512]);
      af[mi] = __builtin_bit_cast(bf16x8, rr);
    }
    #pragma unroll
    for (int ni = 0; ni < 4; ++ni) {
      uint4 rr = *reinterpret_cast<const uint4*>(&Bt[buf][bBase + ni * 512]);
      bfr[ni] = __builtin_bit_cast(bf16x8, rr);
    }
    #pragma unroll
    for (int mi = 0; mi < 4; ++mi)
      #pragma unroll
      for (int ni = 0; ni < 4; ++ni)
        acc[mi][ni] = __builtin_amdgcn_mfma_f32_16x16x32_bf16(af[mi], bfr[ni], acc[mi][ni], 0, 0, 0);
  }

  // ---- epilogue: C/D col = lane&15 (N), row = quad*4+reg (M) ----
  #pragma unroll
  for (int ni = 0; ni < 4; ++ni) {
    const int d = n0 + wn * 64 + ni * 16 + l16;
    const float bv = bias[d];
    #pragma unroll
    for (int mi = 0; mi < 4; ++mi) {
      const int lrow = l0 + wm * 64 + mi * 16 + quad * 4;
      #pragma unroll
      for (int rg = 0; rg < 4; ++rg) {
        out[((size_t)(b * L_DIM + lrow + rg) * 4 + j) * D_DIM + d] = acc[mi][ni][rg] + bv;
      }
    }
  }
}

// ---------------- fallback: round-2 fused kernel (used if ws too small) ----------------
__global__ __launch_bounds__(256, 2) void fused_gemm(
    const unsigned short* __restrict__ XbfZ, const unsigned short* __restrict__ Ball,
    const float* __restrict__ W, const float* __restrict__ bias,
    float* __restrict__ out) {
  __shared__ alignas(16) unsigned short Vt[2][4096];
  __shared__ alignas(16) unsigned short Bt[2][8192];
  __shared__ alignas(16) unsigned short At[128 * 40];
  __shared__ alignas(16) unsigned short Wr[3 * 512];

  const int tid = threadIdx.x;
  const int nt = blockIdx.x & 1;
  const int mt = blockIdx.x >> 1;
  const int j  = mt >> 6;
  const int b  = (mt >> 4) & 3;
  const int lt = mt & 15;
  const int l0 = lt * 128;
  const int n0 = nt * 256;
  const int base_l = l0 - ((j == 3) ? 0 : 1);

  #pragma unroll
  for (int i = 0; i < 6; ++i) {
    const int idx = tid + i * 256;
    const int si = idx >> 9, c = idx & 511, s = 1 << si;
    Wr[idx] = (unsigned short)f2bf(W[j * 512 + ((c - s) & 511)]);
  }

  const int lane = tid & 63, wv = tid >> 6;
  const int qv = (lane & 3) ^ ((lane >> 4) & 3);
  const int rsub = lane >> 2;
  const unsigned short* gA0 = XbfZ + ((size_t)(b * NROWS_X + 1 + base_l + (wv * 2) * 16 + rsub)) * 512 + qv * 8;
  const unsigned short* gA1 = gA0 + (size_t)16 * 512;
  const unsigned short* gB[4];
  #pragma unroll
  for (int pi = 0; pi < 4; ++pi)
    gB[pi] = Ball + (size_t)(j * 512 + n0 + (wv * 4 + pi) * 16 + rsub) * KB_DIM + qv * 8;
  const int vOff0 = wv * 1024 + lane * 8;
  const int bOff0 = wv * 2048 + lane * 8;

  const int am = tid >> 1;
  const int akh = (tid & 1) * 16;
  const int ch0 = (tid & 1) * 2;
  const int sswz = (am >> 2) & 3;
  unsigned short* aDst = &At[am * 40 + akh];

  const int l16 = lane & 15, quad = lane >> 4;
  const int wm = wv >> 1, wn = wv & 1;
  const int fsw = (l16 >> 2) & 3;
  const int aVoff = (wm * 64 + l16) * 32 + ((quad ^ fsw)) * 8;
  const int aSoff = (wm * 64 + l16) * 40 + quad * 8;
  const int bOffF = (wn * 128 + l16) * 32 + ((quad ^ fsw)) * 8;

  f32x4 acc[4][8];
  #pragma unroll
  for (int i = 0; i < 4; ++i)
    #pragma unroll
    for (int n = 0; n < 8; ++n)
      acc[i][n] = f32x4{0.f, 0.f, 0.f, 0.f};

  {
    gld_lds16(gA0, &Vt[0][vOff0]);
    gld_lds16(gA1, &Vt[0][vOff0 + 512]);
    #pragma unroll
    for (int pi = 0; pi < 4; ++pi)
      gld_lds16(gB[pi], &Bt[0][bOff0 + pi * 512]);
  }

  for (int it = 0; it < 64; ++it) {
    const int buf = it & 1;
    const int kk0 = it * 32;
    const int gi = kk0 >> 9;

    __syncthreads();

    if (it + 1 < 64) {
      const int nk = kk0 + 32;
      const int nv = nk & 511;
      gld_lds16(gA0 + nv, &Vt[buf ^ 1][vOff0]);
      gld_lds16(gA1 + nv, &Vt[buf ^ 1][vOff0 + 512]);
      #pragma unroll
      for (int pi = 0; pi < 4; ++pi)
        gld_lds16(gB[pi] + nk, &Bt[buf ^ 1][bOff0 + pi * 512]);
    }

    bf16x8 af[4], bfr[8];
    if (gi == 0) {
      #pragma unroll
      for (int mi = 0; mi < 4; ++mi) {
        uint4 r = *reinterpret_cast<const uint4*>(&Vt[buf][aVoff + mi * 512]);
        af[mi] = __builtin_bit_cast(bf16x8, r);
      }
    } else {
      const int si = gi - 1;
      const int ccbase = (kk0 & 511) + akh;
      uint4 v0 = *reinterpret_cast<const uint4*>(&Vt[buf][(am * 4 + ((ch0)     ^ sswz)) * 8]);
      uint4 v1 = *reinterpret_cast<const uint4*>(&Vt[buf][(am * 4 + ((ch0 + 1) ^ sswz)) * 8]);
      uint4 w0 = *reinterpret_cast<const uint4*>(&Wr[si * 512 + ccbase]);
      uint4 w1 = *reinterpret_cast<const uint4*>(&Wr[si * 512 + ccbase + 8]);
      union U { uint4 q[2]; unsigned short s[16]; };
      U va, wa; va.q[0] = v0; va.q[1] = v1; wa.q[0] = w0; wa.q[1] = w1;
      unsigned res[8];
      #pragma unroll
      for (int e = 0; e < 8; ++e) {
        float s0 = bf2f(va.s[2 * e])     * bf2f(wa.s[2 * e]);
        float s1 = bf2f(va.s[2 * e + 1]) * bf2f(wa.s[2 * e + 1]);
        float g0 = s0 * __builtin_amdgcn_rcpf(1.f + __expf(-s0));
        float g1 = s1 * __builtin_amdgcn_rcpf(1.f + __expf(-s1));
        res[e] = f2bf(g0) | (f2bf(g1) << 16);
      }
      uint4 o0 = {res[0], res[1], res[2], res[3]};
      uint4 o1 = {res[4], res[5], res[6], res[7]};
      *reinterpret_cast<uint4*>(aDst) = o0;
      *reinterpret_cast<uint4*>(aDst + 8) = o1;
      __syncthreads();
      #pragma unroll
      for (int mi = 0; mi < 4; ++mi) {
        uint4 r = *reinterpret_cast<const uint4*>(&At[aSoff + mi * 640]);
        af[mi] = __builtin_bit_cast(bf16x8, r);
      }
    }
    #pragma unroll
    for (int ni = 0; ni < 8; ++ni) {
      uint4 r = *reinterpret_cast<const uint4*>(&Bt[buf][bOffF + ni * 512]);
      bfr[ni] = __builtin_bit_cast(bf16x8, r);
    }
    #pragma unroll
    for (int mi = 0; mi < 4; ++mi)
      #pragma unroll
      for (int ni = 0; ni < 8; ++ni)
        acc[mi][ni] = __builtin_amdgcn_mfma_f32_16x16x32_bf16(af[mi], bfr[ni], acc[mi][ni], 0, 0, 0);
  }

  #pragma unroll
  for (int ni = 0; ni < 8; ++ni) {
    const int d = n0 + wn * 128 + ni * 16 + l16;
    const float bv = bias[d];
    #pragma unroll
    for (int mi = 0; mi < 4; ++mi) {
      const int lrow = l0 + wm * 64 + mi * 16 + quad * 4;
      #pragma unroll
      for (int rg = 0; rg < 4; ++rg) {
        out[((size_t)(b * L_DIM + lrow + rg) * 4 + j) * D_DIM + d] = acc[mi][ni][rg] + bv;
      }
    }
  }
}

extern "C" void kernel_launch(void* const* d_in, const int* in_sizes, int n_in,
                              void* d_out, int out_size, void* d_ws, size_t ws_size,
                              hipStream_t stream) {
  const float* x    = (const float*)d_in[0];  // (4,1,2048,512) fp32
  const float* W    = (const float*)d_in[1];  // (4,512) fp32
  const float* P    = (const float*)d_in[2];  // (3072,512) fp32
  const float* bias = (const float*)d_in[3];  // (512,) fp32
  float* out = (float*)d_out;                 // (4,1,8192,512) fp32

  unsigned short* XbfZ = (unsigned short*)d_ws;                       // 4*2049*512   = 4,196,352 shorts
  unsigned short* Ball = XbfZ + (size_t)4 * NROWS_X * 512;            // 4*512*2048   = 4,194,304
  unsigned short* Wtab = Ball + (size_t)4 * 512 * KB_DIM;             // 6,144
  unsigned short* GS   = Wtab + 6144;                                 // 32768*1536   = 50,331,648
  const size_t need_bytes =
      ((size_t)4 * NROWS_X * 512 + (size_t)4 * 512 * KB_DIM + 6144 +
       (size_t)M_TOT * KS_DIM) * 2;
  const bool primary = ws_size >= need_bytes;

  convert_x<<<dim3(1025, 4), 256, 0, stream>>>(x, XbfZ);
  build_B<<<256, 256, 0, stream>>>(P, W, Ball, Wtab, primary ? 1 : 0);
  if (primary) {
    gs_gen<<<8192, 256, 0, stream>>>(XbfZ, Wtab, GS);
    gemm_main<<<1024, 256, 0, stream>>>(XbfZ, GS, Ball, bias, out);
  } else {
    fused_gemm<<<512, 256, 0, stream>>>(XbfZ, Ball, W, bias, out);
  }
}